// Round 1
// baseline (904.069 us; speedup 1.0000x reference)
//
#include <hip/hip_runtime.h>
#include <hip/hip_bf16.h>

#define SEQ   1440
#define DM    512
#define BEFFN 896
#define CIN   14

typedef unsigned int u32;

__device__ __forceinline__ float bf_lo(u32 u) { union { u32 i; float f; } a; a.i = u << 16;          return a.f; }
__device__ __forceinline__ float bf_hi(u32 u) { union { u32 i; float f; } a; a.i = u & 0xFFFF0000u;  return a.f; }

// v_dot2_f32_bf16 when available (2 FMAs/inst, no unpack); exact-product bf16->fp32 either way.
#if __has_builtin(__builtin_amdgcn_fdot2_f32_bf16)
typedef __bf16 bf16x2 __attribute__((ext_vector_type(2)));
__device__ __forceinline__ float dot2bf(u32 a, u32 b, float c)
{
    union { u32 u; bf16x2 v; } ua, ub; ua.u = a; ub.u = b;
    return __builtin_amdgcn_fdot2_f32_bf16(ua.v, ub.v, c, false);
}
#else
__device__ __forceinline__ float dot2bf(u32 a, u32 b, float c)
{
    c = fmaf(bf_lo(a), bf_lo(b), c);
    c = fmaf(bf_hi(a), bf_hi(b), c);
    return c;
}
#endif

// ---------------------------------------------------------------------------
// dtype probe: bf16 gate rows sum to ~1; fp32 data misread as bf16 does not.
// ---------------------------------------------------------------------------
__global__ void detect_dtype(const void* __restrict__ gates, int* __restrict__ flag)
{
    if (threadIdx.x == 0 && blockIdx.x == 0) {
        const u32* gb = (const u32*)gates;
        float eb = 0.f;
        for (int r = 0; r < 8; ++r) {
            float sb = 0.f;
            for (int k = 0; k < 4; ++k) {
                int idx = r * 4 + k;
                u32 t = gb[idx >> 1];
                sb += (idx & 1) ? bf_hi(t) : bf_lo(t);
            }
            eb += fabsf(sb - 1.f);
        }
        flag[0] = (eb < 0.25f) ? 1 : 0;
    }
}

// ---------------------------------------------------------------------------
// Generic 64-lane batch: lane = row (RB+lane < L), computes 8 outputs at JB.
// Ping-pong 8x uint4 register prefetch keeps 4-8 loads in flight per lane.
// W/bias pointers + JB are wave-uniform (descriptor fetched via readfirstlane)
// so all weight traffic stays on the scalar pipe (s_load).
// ---------------------------------------------------------------------------
__device__ __forceinline__ void batch_bf(const void* __restrict__ x_,
                                         const void* __restrict__ W_,
                                         const void* __restrict__ b_,
                                         float* __restrict__ ylds, int beff,
                                         int L, int P, int RB, int JB, int NACT)
{
    const int lane = threadIdx.x & 63;
    if (lane < NACT) {
        const int l = RB + lane;

        float acc[8];
        {
            const u32* bb = (const u32*)b_ + (JB >> 1);
#pragma unroll
            for (int j = 0; j < 8; j += 2) { u32 t = bb[j >> 1]; acc[j] = bf_lo(t); acc[j + 1] = bf_hi(t); }
        }

        const uint4* xr = (const uint4*)((const __hip_bfloat16*)x_ + ((long long)beff * L + l) * DM);
        const u32*   wp = (const u32*)W_ + ((long long)JB * DM >> 1);

        uint4 va0 = xr[0], va1 = xr[1], va2 = xr[2], va3 = xr[3];
        uint4 vb0 = xr[4], vb1 = xr[5], vb2 = xr[6], vb3 = xr[7];

#define PQ(vq, qk) do {                                             \
        _Pragma("unroll")                                           \
        for (int j = 0; j < 8; ++j) {                               \
            const u32* wr = wp + j * 256 + (qk) * 4;                \
            acc[j] = dot2bf((vq).x, wr[0], acc[j]);                 \
            acc[j] = dot2bf((vq).y, wr[1], acc[j]);                 \
            acc[j] = dot2bf((vq).z, wr[2], acc[j]);                 \
            acc[j] = dot2bf((vq).w, wr[3], acc[j]);                 \
        } } while (0)

#pragma unroll
        for (int g2 = 0; g2 < 8; ++g2) {
            PQ(va0, 0); PQ(va1, 1); PQ(va2, 2); PQ(va3, 3);
            if (g2 < 7) { int q = 8 * (g2 + 1); va0 = xr[q]; va1 = xr[q + 1]; va2 = xr[q + 2]; va3 = xr[q + 3]; }
            PQ(vb0, 4); PQ(vb1, 5); PQ(vb2, 6); PQ(vb3, 7);
            if (g2 < 7) { int q = 8 * (g2 + 1); vb0 = xr[q + 4]; vb1 = xr[q + 5]; vb2 = xr[q + 6]; vb3 = xr[q + 7]; }
            wp += 32;
        }
#undef PQ

        float* yo = ylds + l * P + JB;
        *(float4*)(yo)     = make_float4(acc[0], acc[1], acc[2], acc[3]);
        *(float4*)(yo + 4) = make_float4(acc[4], acc[5], acc[6], acc[7]);
    }
}

__device__ __forceinline__ void batch_f32(const void* __restrict__ x_,
                                          const void* __restrict__ W_,
                                          const void* __restrict__ b_,
                                          float* __restrict__ ylds, int beff,
                                          int L, int P, int RB, int JB, int NACT)
{
    const int lane = threadIdx.x & 63;
    if (lane < NACT) {
        const int l = RB + lane;

        float acc[8];
        {
            const float* bb = (const float*)b_ + JB;
#pragma unroll
            for (int j = 0; j < 8; ++j) acc[j] = bb[j];
        }

        const float4* xr = (const float4*)((const float*)x_ + ((long long)beff * L + l) * DM);
        const float*  wp = (const float*)W_ + (long long)JB * DM;

        float4 va0 = xr[0], va1 = xr[1], va2 = xr[2], va3 = xr[3];
        float4 vb0 = xr[4], vb1 = xr[5], vb2 = xr[6], vb3 = xr[7];

#define PQF(vq, qk) do {                                            \
        _Pragma("unroll")                                           \
        for (int j = 0; j < 8; ++j) {                               \
            const float* wr = wp + j * 512 + (qk) * 4;              \
            acc[j] = fmaf((vq).x, wr[0], acc[j]);                   \
            acc[j] = fmaf((vq).y, wr[1], acc[j]);                   \
            acc[j] = fmaf((vq).z, wr[2], acc[j]);                   \
            acc[j] = fmaf((vq).w, wr[3], acc[j]);                   \
        } } while (0)

#pragma unroll
        for (int g2 = 0; g2 < 16; ++g2) {
            PQF(va0, 0); PQF(va1, 1); PQF(va2, 2); PQF(va3, 3);
            if (g2 < 15) { int q = 8 * (g2 + 1); va0 = xr[q]; va1 = xr[q + 1]; va2 = xr[q + 2]; va3 = xr[q + 3]; }
            PQF(vb0, 4); PQF(vb1, 5); PQF(vb2, 6); PQF(vb3, 7);
            if (g2 < 15) { int q = 8 * (g2 + 1); vb0 = xr[q + 4]; vb1 = xr[q + 5]; vb2 = xr[q + 6]; vb3 = xr[q + 7]; }
            wp += 32;
        }
#undef PQF

        float* yo = ylds + l * P + JB;
        *(float4*)(yo)     = make_float4(acc[0], acc[1], acc[2], acc[3]);
        *(float4*)(yo + 4) = make_float4(acc[4], acc[5], acc[6], acc[7]);
    }
}

// 16 equal-cost batches {scale, L, P, RB, JB, NACT}; wave w runs entries 4w..4w+3.
// Each batch = 64 d-groups x 8 outputs -> identical wave-time; perfect balance.
__device__ const int dtab[16][6] = {
    {0, 180,  8,   0,  0, 64}, {0, 180,  8,  64,  0, 64}, {0, 180,  8, 128,  0, 52}, {1,  90, 16,   0,  0, 64},
    {1,  90, 16,  64,  0, 26}, {1,  90, 16,   0,  8, 64}, {1,  90, 16,  64,  8, 26}, {2,  60, 24,   0,  0, 60},
    {2,  60, 24,   0,  8, 60}, {2,  60, 24,   0, 16, 60}, {3,  30, 48,   0,  0, 30}, {3,  30, 48,   0,  8, 30},
    {3,  30, 48,   0, 16, 30}, {3,  30, 48,   0, 24, 30}, {3,  30, 48,   0, 32, 30}, {3,  30, 48,   0, 40, 30},
};

// ---------------------------------------------------------------------------
// Fused kernel: one block (256 thr = 4 waves) per beff; all 896 blocks
// co-resident (<=4 blocks/CU by VGPR cap, 92KB/CU LDS). Phase 1 fills
// y[4][1440] in LDS, phase 2 does gated log-sum-exp + (B C)S -> B S C.
// ---------------------------------------------------------------------------
__global__ __launch_bounds__(256, 4) void fused_all(
    const void* __restrict__ x0, const void* __restrict__ x1,
    const void* __restrict__ x2, const void* __restrict__ x3,
    const void* __restrict__ W0, const void* __restrict__ W1,
    const void* __restrict__ W2, const void* __restrict__ W3,
    const void* __restrict__ b0, const void* __restrict__ b1,
    const void* __restrict__ b2, const void* __restrict__ b3,
    const void* __restrict__ gates, void* __restrict__ out,
    const int* __restrict__ flag)
{
    __shared__ float ysh[4 * SEQ];     // 23 KB
    const int beff = blockIdx.x;
    const int w = threadIdx.x >> 6;
    const int isbf = flag[0];

#pragma unroll 1
    for (int bi = 0; bi < 4; ++bi) {
        const int e  = __builtin_amdgcn_readfirstlane(w * 4 + bi);
        const int sc = dtab[e][0], L = dtab[e][1], P  = dtab[e][2];
        const int RB = dtab[e][3], JB = dtab[e][4], NA = dtab[e][5];
        const void* xp = sc == 0 ? x0 : sc == 1 ? x1 : sc == 2 ? x2 : x3;
        const void* Wp = sc == 0 ? W0 : sc == 1 ? W1 : sc == 2 ? W2 : W3;
        const void* bp = sc == 0 ? b0 : sc == 1 ? b1 : sc == 2 ? b2 : b3;
        float* yl = ysh + sc * SEQ;
        if (isbf) batch_bf (xp, Wp, bp, yl, beff, L, P, RB, JB, NA);
        else      batch_f32(xp, Wp, bp, yl, beff, L, P, RB, JB, NA);
    }
    __syncthreads();

    const int Bi = beff / CIN, c = beff % CIN;
    float g0, g1, g2, g3;
    if (isbf) {
        const u32* gg = (const u32*)gates;
        u32 t0 = gg[beff * 2], t1 = gg[beff * 2 + 1];
        g0 = bf_lo(t0); g1 = bf_hi(t0); g2 = bf_lo(t1); g3 = bf_hi(t1);
    } else {
        float4 gv = ((const float4*)gates)[beff];
        g0 = gv.x; g1 = gv.y; g2 = gv.z; g3 = gv.w;
    }

    for (int s = threadIdx.x; s < SEQ; s += 256) {
        float acc = g0 * __expf(ysh[s])
                  + g1 * __expf(ysh[SEQ + s])
                  + g2 * __expf(ysh[2 * SEQ + s])
                  + g3 * __expf(ysh[3 * SEQ + s]);
        if (acc == 0.f) acc = 2.2204460492503131e-16f;   // np.finfo(float64).eps
        float r = __logf(acc);
        long long oi = (long long)(Bi * SEQ + s) * CIN + c;
        if (isbf) ((__hip_bfloat16*)out)[oi] = __float2bfloat16(r);
        else      ((float*)out)[oi] = r;
    }
}

extern "C" void kernel_launch(void* const* d_in, const int* in_sizes, int n_in,
                              void* d_out, int out_size, void* d_ws, size_t ws_size,
                              hipStream_t stream)
{
    const void *x[4] = {0,0,0,0}, *W[4] = {0,0,0,0}, *b[4] = {0,0,0,0}, *gates = 0;
    for (int i = 0; i < n_in; ++i) {
        const void* p = d_in[i];
        switch (in_sizes[i]) {
            case 82575360: x[0] = p; break;   // 896*180*512
            case 41287680: x[1] = p; break;   // 896*90*512
            case 27525120: x[2] = p; break;   // 896*60*512
            case 13762560: x[3] = p; break;   // 896*30*512
            case 4096:  W[0] = p; break;      // 8*512
            case 8192:  W[1] = p; break;      // 16*512
            case 12288: W[2] = p; break;      // 24*512
            case 24576: W[3] = p; break;      // 48*512
            case 8:  b[0] = p; break;
            case 16: b[1] = p; break;
            case 24: b[2] = p; break;
            case 48: b[3] = p; break;
            case 3584: gates = p; break;      // 896*4
        }
    }

    int* flag = (int*)d_ws;   // 4 bytes of scratch only

    detect_dtype<<<1, 64, 0, stream>>>(gates, flag);
    fused_all<<<BEFFN, 256, 0, stream>>>(x[0], x[1], x[2], x[3],
                                         W[0], W[1], W[2], W[3],
                                         b[0], b[1], b[2], b[3],
                                         gates, d_out, flag);
}